// Round 9
// baseline (816.016 us; speedup 1.0000x reference)
//
#include <hip/hip_runtime.h>

#define LEAKY 0.2f

typedef __attribute__((ext_vector_type(8))) short short8;   // 8 bf16 (MFMA A/B frag)
typedef __attribute__((ext_vector_type(4))) float floatx4;  // MFMA C/D frag
typedef __attribute__((ext_vector_type(8))) unsigned short ushort8_t;

__device__ __forceinline__ float bf2f(unsigned short u) {
    return __uint_as_float(((unsigned)u) << 16);
}
__device__ __forceinline__ unsigned short f2bf(float f) {
    unsigned u = __float_as_uint(f);
    unsigned r = (u + 0x7fffu + ((u >> 16) & 1u)) >> 16;  // RNE
    return (unsigned short)r;
}
__device__ __forceinline__ float relu_nan(float v) { return v < 0.0f ? 0.0f : v; }

// async global->LDS, 16 B per lane (dest = wave-uniform base + lane*16)
__device__ __forceinline__ void gload_lds16(const void* g, void* l) {
    __builtin_amdgcn_global_load_lds((const __attribute__((address_space(1))) void*)g,
                                     (__attribute__((address_space(3))) void*)l, 16, 0, 0);
}

// device-scope grid barrier (co-resident grid required; separate counter per use).
// Arrival: ONE atomic RMW per block. Poll: device-scope LOADS only (no RMW storm --
// R7/R8 showed same-address RMW polling serializes and scales with #blocks).
__device__ __forceinline__ void gridbar(int* bar, int nblk) {
    __threadfence();                 // release: prior writes visible device-wide
    __syncthreads();
    if (threadIdx.x == 0) {
        __hip_atomic_fetch_add(bar, 1, __ATOMIC_ACQ_REL, __HIP_MEMORY_SCOPE_AGENT);
        while (__hip_atomic_load(bar, __ATOMIC_ACQUIRE, __HIP_MEMORY_SCOPE_AGENT) < nblk)
            __builtin_amdgcn_s_sleep(32);    // ~2k cycles backoff between polls
    }
    __syncthreads();
    __threadfence();                 // acquire
}

// ---------- K_fill (ws-too-small diagnosis) ----------
__global__ void k_fill(float* __restrict__ p, float val, int n) {
    int i = blockIdx.x * blockDim.x + threadIdx.x;
    if (i < n) p[i] = val;
}

// ---------- K_build: transposes + histogram + 2-level scan + scatter, ONE kernel ----------
// grid = 1024 blocks (4 blocks/CU co-resident via __launch_bounds__(256,4): VGPR 12,
// LDS 512B -> occupancy-guaranteed). Full-TLP histogram/scatter; scan phases use the
// first NBS blocks only. cnt and bar pre-zeroed by one memset.
__global__ __launch_bounds__(256, 4) void k_build(
    const float* __restrict__ Wn, unsigned short* __restrict__ WnT,
    const float* __restrict__ W1, unsigned short* __restrict__ W1T,
    const float* __restrict__ W2, unsigned short* __restrict__ W2T,
    const int* __restrict__ src, const int* __restrict__ dst,
    int* __restrict__ cnt, int* __restrict__ rowptr, int* __restrict__ bsum,
    int* __restrict__ wcnt, int* __restrict__ esrc,
    int* __restrict__ bar, int N, int E, int NBS) {
    const int NB = gridDim.x;
    const int gs = NB * 256;
    const int tid = blockIdx.x * 256 + threadIdx.x;
    const int lane = threadIdx.x & 63, wave = threadIdx.x >> 6;
    __shared__ int wtot[4];

    // ---- phase 0: weight transposes + edge histogram (full TLP) ----
    for (int i = tid; i < 256 * 128; i += gs) {   // WnT[col][k], col=head*64+d
        int col = i >> 7, k = i & 127;
        int head = col >> 6, d = col & 63;
        WnT[i] = f2bf(Wn[(size_t)head * 8192 + (size_t)k * 64 + d]);
    }
    for (int i = tid; i < 256 * 256; i += gs) {   // W1T[n][k] = W1[k][n]
        int n = i >> 8, k = i & 255;
        W1T[i] = f2bf(W1[(size_t)k * 256 + n]);
    }
    for (int i = tid; i < 128 * 256; i += gs) {   // W2T[n][k] = W2[k][n]
        int n = i >> 8, k = i & 255;
        W2T[i] = f2bf(W2[(size_t)k * 128 + n]);
    }
    for (int e = tid; e < E; e += gs) atomicAdd(cnt + dst[e], 1);
    gridbar(bar + 0, NB);

    // ---- phase 1: per-chunk exclusive scan (first NBS blocks) ----
    if (blockIdx.x < NBS) {
        const int i = blockIdx.x * 256 + threadIdx.x;
        int v = (i < N) ? cnt[i] : 0;
        int x = v;
        for (int off = 1; off < 64; off <<= 1) {
            int y = __shfl_up(x, off, 64);
            if (lane >= off) x += y;
        }
        if (lane == 63) wtot[wave] = x;
        __syncthreads();
        int wo = 0;
        for (int wv = 0; wv < wave; ++wv) wo += wtot[wv];
        if (i < N) rowptr[i] = wo + x - v;          // local exclusive
        if (threadIdx.x == 255) bsum[blockIdx.x] = wo + x;
        __syncthreads();                            // wtot reused below
    }
    gridbar(bar + 1, NB);

    // ---- phase 2: add global prefix (redundant reduce of bsum; first NBS blocks) ----
    if (blockIdx.x < NBS) {
        const int b = blockIdx.x;
        int v = (threadIdx.x < b) ? bsum[threadIdx.x] : 0;   // b < NBS <= 256
#pragma unroll
        for (int m = 32; m >= 1; m >>= 1) v += __shfl_xor(v, m, 64);
        if (lane == 0) wtot[wave] = v;
        __syncthreads();
        const int s_pre = wtot[0] + wtot[1] + wtot[2] + wtot[3];
        const int gi = b * 256 + threadIdx.x;
        if (gi < N) {
            int r = rowptr[gi] + s_pre;
            rowptr[gi] = r;
            wcnt[gi] = r;
        }
        if (b == NBS - 1 && threadIdx.x == 255) rowptr[N] = E;
    }
    gridbar(bar + 2, NB);

    // ---- phase 3: scatter src ids into CSR order (full TLP) ----
    for (int e = tid; e < E; e += gs) {
        int pos = atomicAdd(wcnt + dst[e], 1);
        esrc[pos] = src[e];
    }
}

// ---------- K_agg: per-dst gather-aggregate -> concat (bf16) ----------
// One dst row per wave (fine-grained balance); next-block esrc/s_src meta
// prefetched before the inner loop so the dependent chain overlaps the gathers.
__global__ __launch_bounds__(256) void k_agg(
    const float* __restrict__ s_src, const float* __restrict__ s_dst,
    const unsigned short* __restrict__ h_bf,
    const int* __restrict__ rowptr, const int* __restrict__ esrc,
    unsigned short* __restrict__ concat, int N) {
    const int t = threadIdx.x;
    const int lane = t & 63;
    const int wave = t >> 6;
    const int n = blockIdx.x * 4 + wave;
    if (n >= N) return;

    const int head = lane >> 4;
    const int c0 = lane << 2;
    const int eslot = lane & 15;
    const int hsel = lane & 48;

    const int beg = rowptr[n], end = rowptr[n + 1];
    const float sdst = s_dst[n * 4 + head];
    float num0 = 0, num1 = 0, num2 = 0, num3 = 0, den = 0;

    // prefetch block 0 meta
    int sid = 0;
    float sv = 0.0f;
    if (beg < end && eslot < end - beg) {
        sid = esrc[beg + eslot];
        sv = s_src[sid * 4 + head];
    }

    for (int base = beg; base < end; base += 16) {
        const int nn = end - base;
        // prefetch next block meta (overlaps inner loop below)
        int sidn = 0;
        float svn = 0.0f;
        if (base + 16 < end) {
            if (eslot < end - (base + 16)) {
                sidn = esrc[base + 16 + eslot];
                svn = s_src[sidn * 4 + head];
            }
        }
        float my_ex = 0.0f;
        if (eslot < nn) {
            float v = sv + sdst;
            v = fmaxf(v, LEAKY * v);
            my_ex = __expf(v);
        }
#pragma unroll
        for (int e = 0; e < 16; ++e) {
            float ex = __shfl(my_ex, hsel | e, 64);
            int s    = __shfl(sid, e, 64);
            ushort4 hv = *(const ushort4*)(h_bf + (size_t)s * 256 + c0);
            num0 += ex * bf2f(hv.x);
            num1 += ex * bf2f(hv.y);
            num2 += ex * bf2f(hv.z);
            num3 += ex * bf2f(hv.w);
            den  += ex;
        }
        sid = sidn; sv = svn;
    }

    const float inv = 1.0f / (den > 0.0f ? den : 1.0f);
    ushort4 o;
    o.x = f2bf(relu_nan(num0 * inv));
    o.y = f2bf(relu_nan(num1 * inv));
    o.z = f2bf(relu_nan(num2 * inv));
    o.w = f2bf(relu_nan(num3 * inv));
    *(ushort4*)(concat + (size_t)n * 256 + c0) = o;
}

// ---------- K_gemm0: h = bf16(X) @ WnT, fused attention-score epilogue ----------
// A is fp32 X, converted to bf16 during reg-staged LDS write. Each wave owns
// one head's 64 cols for the score epilogue.
__global__ __launch_bounds__(256) void k_gemm0(
    const float* __restrict__ A, const unsigned short* __restrict__ BT,
    unsigned short* __restrict__ Cb, int N,
    const float* __restrict__ asrc, const float* __restrict__ adst,
    float* __restrict__ s_src, float* __restrict__ s_dst) {
    __shared__ unsigned short As[128 * 32];
    __shared__ unsigned short Bs[128 * 32];
    const int t = threadIdx.x;
    const int lane = t & 63;
    const int w = t >> 6;
    const int wy = w >> 1, wx = w & 1;
    const int lm = lane & 15, quad = lane >> 4;
    const int row0 = blockIdx.x * 128;
    const int n0 = blockIdx.y * 128;
    const int srow = lane >> 2;
    const int sk = (lane & 3) * 8;

    floatx4 acc[4][4];
#pragma unroll
    for (int mi = 0; mi < 4; ++mi)
#pragma unroll
        for (int ni = 0; ni < 4; ++ni) acc[mi][ni] = (floatx4){0, 0, 0, 0};

    for (int k0 = 0; k0 < 128; k0 += 32) {
#pragma unroll
        for (int p = 0; p < 2; ++p) {
            int tr = (p * 4 + w) * 16 + srow;
            int ga = row0 + tr; if (ga >= N) ga = N - 1;   // clamp (stores guarded)
            float4 v0 = *(const float4*)(A + (size_t)ga * 128 + k0 + sk);
            float4 v1 = *(const float4*)(A + (size_t)ga * 128 + k0 + sk + 4);
            short8 pk;
            pk[0] = (short)f2bf(v0.x); pk[1] = (short)f2bf(v0.y);
            pk[2] = (short)f2bf(v0.z); pk[3] = (short)f2bf(v0.w);
            pk[4] = (short)f2bf(v1.x); pk[5] = (short)f2bf(v1.y);
            pk[6] = (short)f2bf(v1.z); pk[7] = (short)f2bf(v1.w);
            *(short8*)(As + (size_t)tr * 32 + sk) = pk;
            gload_lds16(BT + (size_t)(n0 + tr) * 128 + k0 + sk,
                        (char*)Bs + (size_t)tr * 64 + sk * 2);
        }
        __syncthreads();
        short8 af[4], bfr[4];
#pragma unroll
        for (int mi = 0; mi < 4; ++mi)
            af[mi] = *(const short8*)(As + (size_t)(wy * 64 + mi * 16 + lm) * 32 + quad * 8);
#pragma unroll
        for (int ni = 0; ni < 4; ++ni)
            bfr[ni] = *(const short8*)(Bs + (size_t)(wx * 64 + ni * 16 + lm) * 32 + quad * 8);
#pragma unroll
        for (int mi = 0; mi < 4; ++mi)
#pragma unroll
            for (int ni = 0; ni < 4; ++ni)
                acc[mi][ni] = __builtin_amdgcn_mfma_f32_16x16x32_bf16(af[mi], bfr[ni], acc[mi][ni], 0, 0, 0);
        __syncthreads();
    }

#pragma unroll
    for (int mi = 0; mi < 4; ++mi)
#pragma unroll
        for (int ni = 0; ni < 4; ++ni)
#pragma unroll
            for (int q = 0; q < 4; ++q) {
                int r = row0 + wy * 64 + mi * 16 + quad * 4 + q;
                int c = n0 + wx * 64 + ni * 16 + lm;
                if (r < N) Cb[(size_t)r * 256 + c] = f2bf(acc[mi][ni][q]);
            }

    // fused attention-score epilogue: this wave's 64 cols = one full head
    const int head = blockIdx.y * 2 + wx;
    float as[4], ad[4];
#pragma unroll
    for (int ni = 0; ni < 4; ++ni) {
        int d = ni * 16 + lm;
        as[ni] = asrc[head * 64 + d];
        ad[ni] = adst[head * 64 + d];
    }
#pragma unroll
    for (int mi = 0; mi < 4; ++mi)
#pragma unroll
        for (int q = 0; q < 4; ++q) {
            float ps = acc[mi][0][q] * as[0] + acc[mi][1][q] * as[1]
                     + acc[mi][2][q] * as[2] + acc[mi][3][q] * as[3];
            float pd = acc[mi][0][q] * ad[0] + acc[mi][1][q] * ad[1]
                     + acc[mi][2][q] * ad[2] + acc[mi][3][q] * ad[3];
#pragma unroll
            for (int m = 1; m < 16; m <<= 1) {
                ps += __shfl_xor(ps, m, 64);
                pd += __shfl_xor(pd, m, 64);
            }
            if (lm == 0) {
                int r = row0 + wy * 64 + mi * 16 + quad * 4 + q;
                if (r < N) {
                    s_src[r * 4 + head] = ps;
                    s_dst[r * 4 + head] = pd;
                }
            }
        }
}

// ---------- K_mlp: fused MLP  out = (relu(concat@W1+b1))@W2 + b2 ----------
// One block = 64 rows. Stage 1: hidden(64x256) in-register (waves split cols),
// relu -> bf16 -> LDS Hs[64][264] (+8 pad). Stage 2: Hs @ W2T -> out(64x128) f32.
// In-place safe: block reads exactly concat rows [r0,r0+64) (same d_out bytes
// it later writes as f32 out); clamp row N-1 lies in the last block's range.
__global__ __launch_bounds__(256) void k_mlp(
    const unsigned short* __restrict__ concat,   // [N][256] bf16 (in d_out)
    const unsigned short* __restrict__ W1T,      // [256][256] bf16 [n][k]
    const float* __restrict__ b1,
    const unsigned short* __restrict__ W2T,      // [128][256] bf16 [n][k]
    const float* __restrict__ b2,
    float* __restrict__ outp, int N) {           // [N][128] f32 (same bytes)
    __shared__ unsigned short As[64 * 32];       // 4 KB
    __shared__ unsigned short Bs[256 * 32];      // 16 KB (stage 2 reuses 8 KB)
    __shared__ unsigned short Hs[64 * 264];      // 33 KB (+8 pad per row)
    const int t = threadIdx.x;
    const int lane = t & 63;
    const int w = t >> 6;
    const int lm = lane & 15, quad = lane >> 4;
    const int row0 = blockIdx.x * 64;
    const int tr = t >> 2;          // 0..63
    const int sk = (t & 3) * 8;     // k-element offset

    // ---- stage 1: hidden = relu(concat @ W1 + b1), wave w owns cols w*64.. ----
    floatx4 acc[4][4];
#pragma unroll
    for (int ni = 0; ni < 4; ++ni) {
        float b = b1[w * 64 + ni * 16 + lm];
#pragma unroll
        for (int mi = 0; mi < 4; ++mi) acc[mi][ni] = (floatx4){b, b, b, b};
    }

    for (int k0 = 0; k0 < 256; k0 += 32) {
        {   // A: 64 rows x 32 k
            int ga = row0 + tr; if (ga >= N) ga = N - 1;
            gload_lds16(concat + (size_t)ga * 256 + k0 + sk,
                        (char*)As + (size_t)tr * 64 + sk * 2);
        }
#pragma unroll
        for (int p = 0; p < 4; ++p) {   // B: 256 rows of W1T
            int rn = p * 64 + tr;
            gload_lds16(W1T + (size_t)rn * 256 + k0 + sk,
                        (char*)Bs + (size_t)rn * 64 + sk * 2);
        }
        __syncthreads();
        short8 af[4], bfr[4];
#pragma unroll
        for (int mi = 0; mi < 4; ++mi)
            af[mi] = *(const short8*)(As + (size_t)(mi * 16 + lm) * 32 + quad * 8);
#pragma unroll
        for (int ni = 0; ni < 4; ++ni)
            bfr[ni] = *(const short8*)(Bs + (size_t)(w * 64 + ni * 16 + lm) * 32 + quad * 8);
#pragma unroll
        for (int mi = 0; mi < 4; ++mi)
#pragma unroll
            for (int ni = 0; ni < 4; ++ni)
                acc[mi][ni] = __builtin_amdgcn_mfma_f32_16x16x32_bf16(af[mi], bfr[ni], acc[mi][ni], 0, 0, 0);
        __syncthreads();
    }

    // hidden -> Hs (relu, bf16)
#pragma unroll
    for (int mi = 0; mi < 4; ++mi)
#pragma unroll
        for (int ni = 0; ni < 4; ++ni)
#pragma unroll
            for (int q = 0; q < 4; ++q) {
                int row = mi * 16 + quad * 4 + q;
                int col = w * 64 + ni * 16 + lm;
                Hs[row * 264 + col] = f2bf(relu_nan(acc[mi][ni][q]));
            }

    // ---- stage 2: out = Hs @ W2 + b2, wave w owns cols w*32.. ----
    floatx4 acc2[4][2];
#pragma unroll
    for (int ni = 0; ni < 2; ++ni) {
        float b = b2[w * 32 + ni * 16 + lm];
#pragma unroll
        for (int mi = 0; mi < 4; ++mi) acc2[mi][ni] = (floatx4){b, b, b, b};
    }

    for (int k0 = 0; k0 < 256; k0 += 32) {
#pragma unroll
        for (int p = 0; p < 2; ++p) {   // B: 128 rows of W2T
            int rn = p * 64 + tr;
            gload_lds16(W2T + (size_t)rn * 256 + k0 + sk,
                        (char*)Bs + (size_t)rn * 64 + sk * 2);
        }
        __syncthreads();   // Bs2 staged AND (k0==0) Hs writes visible to all waves
        short8 af[4], bfr[2];
#pragma unroll
        for (int mi = 0; mi < 4; ++mi)
            af[mi] = *(const short8*)(Hs + (size_t)(mi * 16 + lm) * 264 + k0 + quad * 8);
#pragma unroll
        for (int ni = 0; ni < 2; ++ni)
            bfr[ni] = *(const short8*)(Bs + (size_t)(w * 32 + ni * 16 + lm) * 32 + quad * 8);
#pragma unroll
        for (int mi = 0; mi < 4; ++mi)
#pragma unroll
            for (int ni = 0; ni < 2; ++ni)
                acc2[mi][ni] = __builtin_amdgcn_mfma_f32_16x16x32_bf16(af[mi], bfr[ni], acc2[mi][ni], 0, 0, 0);
        __syncthreads();
    }

#pragma unroll
    for (int mi = 0; mi < 4; ++mi)
#pragma unroll
        for (int ni = 0; ni < 2; ++ni)
#pragma unroll
            for (int q = 0; q < 4; ++q) {
                int r = row0 + mi * 16 + quad * 4 + q;
                int c = w * 32 + ni * 16 + lm;
                if (r < N) outp[(size_t)r * 128 + c] = acc2[mi][ni][q];
            }
}

extern "C" void kernel_launch(void* const* d_in, const int* in_sizes, int n_in,
                              void* d_out, int out_size, void* d_ws, size_t ws_size,
                              hipStream_t stream) {
    const float* X    = (const float*)d_in[0];
    const int* src    = (const int*)d_in[1];
    const int* dst    = (const int*)d_in[2];
    const float* Wn   = (const float*)d_in[3];
    const float* Asrc = (const float*)d_in[4];
    const float* Adst = (const float*)d_in[5];
    const float* W1   = (const float*)d_in[6];
    const float* b1   = (const float*)d_in[7];
    const float* W2   = (const float*)d_in[8];
    const float* b2   = (const float*)d_in[9];
    float* out = (float*)d_out;

    const int N = in_sizes[0] / 128;   // 50000
    const int E = in_sizes[1];         // 800000
    const int NBS = (N + 255) / 256;   // scan chunks (must be <= 256)
    const int NBB = 1024;              // k_build grid: 4 blocks/CU co-resident
    const int NR = (N + 127) / 128;    // gemm0 row tiles
    const int NM = (N + 63) / 64;      // k_mlp row tiles

    // ws layout (16B-aligned offsets), ~31 MB. cnt and bar contiguous (one memset).
    size_t off = 0;
    char* w = (char*)d_ws;
    unsigned short* h_bf = (unsigned short*)(w + off); off += (size_t)N * 256 * 2;
    float* s_src = (float*)(w + off);                  off += (size_t)N * 4 * 4;
    float* s_dst = (float*)(w + off);                  off += (size_t)N * 4 * 4;
    int* cnt     = (int*)(w + off);                    off += (size_t)N * 4;
    int* bar     = (int*)(w + off);                    off += 16;
    int* rowptr  = (int*)(w + off);                    off += ((size_t)(N + 1) * 4 + 15) & ~15ull;
    int* wcnt    = (int*)(w + off);                    off += (size_t)N * 4;
    int* bsum    = (int*)(w + off);                    off += ((size_t)NBS * 4 + 15) & ~15ull;
    int* esrc    = (int*)(w + off);                    off += (size_t)E * 4;
    unsigned short* W1T = (unsigned short*)(w + off);  off += 256 * 256 * 2;
    unsigned short* W2T = (unsigned short*)(w + off);  off += 128 * 256 * 2;
    unsigned short* WnT = (unsigned short*)(w + off);  off += 256 * 128 * 2;
    const size_t required = off;

    if (ws_size < required) {
        k_fill<<<dim3((out_size + 255) / 256), dim3(256), 0, stream>>>(
            out, (float)(ws_size >> 20), out_size);
        return;
    }

    // d_out staging: concat (bf16 [N,256]) from k_agg -> consumed in-place by k_mlp,
    // which overwrites the same bytes with the final fp32 out.
    unsigned short* concat = (unsigned short*)d_out;

    // zero cnt + bar in one memset (bar immediately follows cnt)
    hipMemsetAsync(cnt, 0, (size_t)N * sizeof(int) + 16, stream);
    // CSR build: transposes + hist + scan + scatter (one resident kernel, full TLP)
    k_build<<<dim3(NBB), dim3(256), 0, stream>>>(
        Wn, WnT, W1, W1T, W2, W2T, src, dst, cnt, rowptr, bsum, wcnt, esrc, bar,
        N, E, NBS);
    // h = bf16(X) @ WnT (MFMA, A staged from fp32) + fused s_src/s_dst epilogue
    k_gemm0<<<dim3(NR, 2), dim3(256), 0, stream>>>(
        X, WnT, h_bf, N, Asrc, Adst, s_src, s_dst);
    k_agg<<<dim3((N + 3) / 4), dim3(256), 0, stream>>>(s_src, s_dst, h_bf, rowptr, esrc,
                                                       concat, N);
    // fused MLP: out = relu(concat @ W1 + b1) @ W2 + b2   (in-place in d_out)
    k_mlp<<<dim3(NM), dim3(256), 0, stream>>>(concat, W1T, b1, W2T, b2, out, N);
}

// Round 10
// 289.331 us; speedup vs baseline: 2.8204x; 2.8204x over previous
//
#include <hip/hip_runtime.h>

#define LEAKY 0.2f

typedef __attribute__((ext_vector_type(8))) short short8;   // 8 bf16 (MFMA A/B frag)
typedef __attribute__((ext_vector_type(4))) float floatx4;  // MFMA C/D frag
typedef __attribute__((ext_vector_type(8))) unsigned short ushort8_t;

__device__ __forceinline__ float bf2f(unsigned short u) {
    return __uint_as_float(((unsigned)u) << 16);
}
__device__ __forceinline__ unsigned short f2bf(float f) {
    unsigned u = __float_as_uint(f);
    unsigned r = (u + 0x7fffu + ((u >> 16) & 1u)) >> 16;  // RNE
    return (unsigned short)r;
}
__device__ __forceinline__ float relu_nan(float v) { return v < 0.0f ? 0.0f : v; }

// async global->LDS, 16 B per lane (dest = wave-uniform base + lane*16)
__device__ __forceinline__ void gload_lds16(const void* g, void* l) {
    __builtin_amdgcn_global_load_lds((const __attribute__((address_space(1))) void*)g,
                                     (__attribute__((address_space(3))) void*)l, 16, 0, 0);
}

// ---------- K_fill (ws-too-small diagnosis) ----------
__global__ void k_fill(float* __restrict__ p, float val, int n) {
    int i = blockIdx.x * blockDim.x + threadIdx.x;
    if (i < n) p[i] = val;
}

// ---------- K_prep: weight transposes + edge histogram (cnt pre-zeroed by memset) ----------
__global__ void k_prep(const float* __restrict__ Wn, unsigned short* __restrict__ WnT,
                       const float* __restrict__ W1, unsigned short* __restrict__ W1T,
                       const float* __restrict__ W2, unsigned short* __restrict__ W2T,
                       const int* __restrict__ dst, int* __restrict__ cnt, int E) {
    const int gs = gridDim.x * blockDim.x;
    const int tid = blockIdx.x * blockDim.x + threadIdx.x;
    for (int i = tid; i < 256 * 128; i += gs) {   // WnT[col][k], col=head*64+d
        int col = i >> 7, k = i & 127;
        int head = col >> 6, d = col & 63;
        WnT[i] = f2bf(Wn[(size_t)head * 8192 + (size_t)k * 64 + d]);
    }
    for (int i = tid; i < 256 * 256; i += gs) {   // W1T[n][k] = W1[k][n]
        int n = i >> 8, k = i & 255;
        W1T[i] = f2bf(W1[(size_t)k * 256 + n]);
    }
    for (int i = tid; i < 128 * 256; i += gs) {   // W2T[n][k] = W2[k][n]
        int n = i >> 8, k = i & 255;
        W2T[i] = f2bf(W2[(size_t)k * 128 + n]);
    }
    for (int i = tid; i < E; i += gs) atomicAdd(cnt + dst[i], 1);  // histogram
}

// ---------- K_scan1: per-block exclusive scan + block sums ----------
__global__ __launch_bounds__(256) void k_scan1(
    const int* __restrict__ cnt, int* __restrict__ rowptr, int* __restrict__ bsum, int N) {
    __shared__ int wtot[4];
    const int lane = threadIdx.x & 63, wave = threadIdx.x >> 6;
    const int i = blockIdx.x * 256 + threadIdx.x;
    int v = (i < N) ? cnt[i] : 0;
    int x = v;
    for (int off = 1; off < 64; off <<= 1) {
        int y = __shfl_up(x, off, 64);
        if (lane >= off) x += y;
    }
    if (lane == 63) wtot[wave] = x;
    __syncthreads();
    int wo = 0;
    for (int wv = 0; wv < wave; ++wv) wo += wtot[wv];
    if (i < N) rowptr[i] = wo + x - v;
    if (threadIdx.x == 255) bsum[blockIdx.x] = wo + x;
}

// ---------- K_scan23: each block redundantly reduces its bsum prefix, finalizes ----------
// (phase-2 logic correctness-verified inside k_build in R7/R8/R9; NBS <= 256)
__global__ __launch_bounds__(256) void k_scan23(
    int* __restrict__ rowptr, const int* __restrict__ bsum,
    int* __restrict__ wcnt, int N, int E) {
    __shared__ int wtot[4];
    const int lane = threadIdx.x & 63, wave = threadIdx.x >> 6;
    const int b = blockIdx.x;
    int v = (threadIdx.x < b) ? bsum[threadIdx.x] : 0;
#pragma unroll
    for (int m = 32; m >= 1; m >>= 1) v += __shfl_xor(v, m, 64);
    if (lane == 0) wtot[wave] = v;
    __syncthreads();
    const int s_pre = wtot[0] + wtot[1] + wtot[2] + wtot[3];
    const int gi = b * 256 + threadIdx.x;
    if (gi < N) {
        int r = rowptr[gi] + s_pre;
        rowptr[gi] = r;
        wcnt[gi] = r;
    }
    if (b == gridDim.x - 1 && threadIdx.x == 255) rowptr[N] = E;
}

// ---------- K_scatter: src ids into CSR order ----------
__global__ void k_scatter(const int* __restrict__ src, const int* __restrict__ dst,
                          int* __restrict__ wcnt, int* __restrict__ esrc, int E) {
    int e = blockIdx.x * blockDim.x + threadIdx.x;
    if (e < E) {
        int pos = atomicAdd(wcnt + dst[e], 1);
        esrc[pos] = src[e];
    }
}

// ---------- K_agg: per-dst gather-aggregate -> concat (bf16) ----------
// One dst row per wave (fine-grained balance); next-block esrc/s_src meta
// prefetched before the inner loop so the dependent chain overlaps the gathers.
__global__ __launch_bounds__(256) void k_agg(
    const float* __restrict__ s_src, const float* __restrict__ s_dst,
    const unsigned short* __restrict__ h_bf,
    const int* __restrict__ rowptr, const int* __restrict__ esrc,
    unsigned short* __restrict__ concat, int N) {
    const int t = threadIdx.x;
    const int lane = t & 63;
    const int wave = t >> 6;
    const int n = blockIdx.x * 4 + wave;
    if (n >= N) return;

    const int head = lane >> 4;
    const int c0 = lane << 2;
    const int eslot = lane & 15;
    const int hsel = lane & 48;

    const int beg = rowptr[n], end = rowptr[n + 1];
    const float sdst = s_dst[n * 4 + head];
    float num0 = 0, num1 = 0, num2 = 0, num3 = 0, den = 0;

    // prefetch block 0 meta
    int sid = 0;
    float sv = 0.0f;
    if (beg < end && eslot < end - beg) {
        sid = esrc[beg + eslot];
        sv = s_src[sid * 4 + head];
    }

    for (int base = beg; base < end; base += 16) {
        const int nn = end - base;
        // prefetch next block meta (overlaps inner loop below)
        int sidn = 0;
        float svn = 0.0f;
        if (base + 16 < end) {
            if (eslot < end - (base + 16)) {
                sidn = esrc[base + 16 + eslot];
                svn = s_src[sidn * 4 + head];
            }
        }
        float my_ex = 0.0f;
        if (eslot < nn) {
            float v = sv + sdst;
            v = fmaxf(v, LEAKY * v);
            my_ex = __expf(v);
        }
#pragma unroll
        for (int e = 0; e < 16; ++e) {
            float ex = __shfl(my_ex, hsel | e, 64);
            int s    = __shfl(sid, e, 64);
            ushort4 hv = *(const ushort4*)(h_bf + (size_t)s * 256 + c0);
            num0 += ex * bf2f(hv.x);
            num1 += ex * bf2f(hv.y);
            num2 += ex * bf2f(hv.z);
            num3 += ex * bf2f(hv.w);
            den  += ex;
        }
        sid = sidn; sv = svn;
    }

    const float inv = 1.0f / (den > 0.0f ? den : 1.0f);
    ushort4 o;
    o.x = f2bf(relu_nan(num0 * inv));
    o.y = f2bf(relu_nan(num1 * inv));
    o.z = f2bf(relu_nan(num2 * inv));
    o.w = f2bf(relu_nan(num3 * inv));
    *(ushort4*)(concat + (size_t)n * 256 + c0) = o;
}

// ---------- K_gemm0: h = bf16(X) @ WnT, fused attention-score epilogue ----------
// A is fp32 X, converted to bf16 during reg-staged LDS write. Each wave owns
// one head's 64 cols for the score epilogue.
__global__ __launch_bounds__(256) void k_gemm0(
    const float* __restrict__ A, const unsigned short* __restrict__ BT,
    unsigned short* __restrict__ Cb, int N,
    const float* __restrict__ asrc, const float* __restrict__ adst,
    float* __restrict__ s_src, float* __restrict__ s_dst) {
    __shared__ unsigned short As[128 * 32];
    __shared__ unsigned short Bs[128 * 32];
    const int t = threadIdx.x;
    const int lane = t & 63;
    const int w = t >> 6;
    const int wy = w >> 1, wx = w & 1;
    const int lm = lane & 15, quad = lane >> 4;
    const int row0 = blockIdx.x * 128;
    const int n0 = blockIdx.y * 128;
    const int srow = lane >> 2;
    const int sk = (lane & 3) * 8;

    floatx4 acc[4][4];
#pragma unroll
    for (int mi = 0; mi < 4; ++mi)
#pragma unroll
        for (int ni = 0; ni < 4; ++ni) acc[mi][ni] = (floatx4){0, 0, 0, 0};

    for (int k0 = 0; k0 < 128; k0 += 32) {
#pragma unroll
        for (int p = 0; p < 2; ++p) {
            int tr = (p * 4 + w) * 16 + srow;
            int ga = row0 + tr; if (ga >= N) ga = N - 1;   // clamp (stores guarded)
            float4 v0 = *(const float4*)(A + (size_t)ga * 128 + k0 + sk);
            float4 v1 = *(const float4*)(A + (size_t)ga * 128 + k0 + sk + 4);
            short8 pk;
            pk[0] = (short)f2bf(v0.x); pk[1] = (short)f2bf(v0.y);
            pk[2] = (short)f2bf(v0.z); pk[3] = (short)f2bf(v0.w);
            pk[4] = (short)f2bf(v1.x); pk[5] = (short)f2bf(v1.y);
            pk[6] = (short)f2bf(v1.z); pk[7] = (short)f2bf(v1.w);
            *(short8*)(As + (size_t)tr * 32 + sk) = pk;
            gload_lds16(BT + (size_t)(n0 + tr) * 128 + k0 + sk,
                        (char*)Bs + (size_t)tr * 64 + sk * 2);
        }
        __syncthreads();
        short8 af[4], bfr[4];
#pragma unroll
        for (int mi = 0; mi < 4; ++mi)
            af[mi] = *(const short8*)(As + (size_t)(wy * 64 + mi * 16 + lm) * 32 + quad * 8);
#pragma unroll
        for (int ni = 0; ni < 4; ++ni)
            bfr[ni] = *(const short8*)(Bs + (size_t)(wx * 64 + ni * 16 + lm) * 32 + quad * 8);
#pragma unroll
        for (int mi = 0; mi < 4; ++mi)
#pragma unroll
            for (int ni = 0; ni < 4; ++ni)
                acc[mi][ni] = __builtin_amdgcn_mfma_f32_16x16x32_bf16(af[mi], bfr[ni], acc[mi][ni], 0, 0, 0);
        __syncthreads();
    }

#pragma unroll
    for (int mi = 0; mi < 4; ++mi)
#pragma unroll
        for (int ni = 0; ni < 4; ++ni)
#pragma unroll
            for (int q = 0; q < 4; ++q) {
                int r = row0 + wy * 64 + mi * 16 + quad * 4 + q;
                int c = n0 + wx * 64 + ni * 16 + lm;
                if (r < N) Cb[(size_t)r * 256 + c] = f2bf(acc[mi][ni][q]);
            }

    // fused attention-score epilogue: this wave's 64 cols = one full head
    const int head = blockIdx.y * 2 + wx;
    float as[4], ad[4];
#pragma unroll
    for (int ni = 0; ni < 4; ++ni) {
        int d = ni * 16 + lm;
        as[ni] = asrc[head * 64 + d];
        ad[ni] = adst[head * 64 + d];
    }
#pragma unroll
    for (int mi = 0; mi < 4; ++mi)
#pragma unroll
        for (int q = 0; q < 4; ++q) {
            float ps = acc[mi][0][q] * as[0] + acc[mi][1][q] * as[1]
                     + acc[mi][2][q] * as[2] + acc[mi][3][q] * as[3];
            float pd = acc[mi][0][q] * ad[0] + acc[mi][1][q] * ad[1]
                     + acc[mi][2][q] * ad[2] + acc[mi][3][q] * ad[3];
#pragma unroll
            for (int m = 1; m < 16; m <<= 1) {
                ps += __shfl_xor(ps, m, 64);
                pd += __shfl_xor(pd, m, 64);
            }
            if (lm == 0) {
                int r = row0 + wy * 64 + mi * 16 + quad * 4 + q;
                if (r < N) {
                    s_src[r * 4 + head] = ps;
                    s_dst[r * 4 + head] = pd;
                }
            }
        }
}

// ---------- K_mlp: fused MLP  out = (relu(concat@W1+b1))@W2 + b2 ----------
// One block = 64 rows. Stage 1: hidden(64x256) in-register (waves split cols),
// relu -> bf16 -> LDS Hs[64][264] (+8 pad). Stage 2: Hs @ W2T -> out(64x128) f32.
// In-place safe: block reads exactly concat rows [r0,r0+64) (same d_out bytes
// it later writes as f32 out); clamp row N-1 lies in the last block's range.
__global__ __launch_bounds__(256) void k_mlp(
    const unsigned short* __restrict__ concat,   // [N][256] bf16 (in d_out)
    const unsigned short* __restrict__ W1T,      // [256][256] bf16 [n][k]
    const float* __restrict__ b1,
    const unsigned short* __restrict__ W2T,      // [128][256] bf16 [n][k]
    const float* __restrict__ b2,
    float* __restrict__ outp, int N) {           // [N][128] f32 (same bytes)
    __shared__ unsigned short As[64 * 32];       // 4 KB
    __shared__ unsigned short Bs[256 * 32];      // 16 KB (stage 2 reuses 8 KB)
    __shared__ unsigned short Hs[64 * 264];      // 33 KB (+8 pad per row)
    const int t = threadIdx.x;
    const int lane = t & 63;
    const int w = t >> 6;
    const int lm = lane & 15, quad = lane >> 4;
    const int row0 = blockIdx.x * 64;
    const int tr = t >> 2;          // 0..63
    const int sk = (t & 3) * 8;     // k-element offset

    // ---- stage 1: hidden = relu(concat @ W1 + b1), wave w owns cols w*64.. ----
    floatx4 acc[4][4];
#pragma unroll
    for (int ni = 0; ni < 4; ++ni) {
        float b = b1[w * 64 + ni * 16 + lm];
#pragma unroll
        for (int mi = 0; mi < 4; ++mi) acc[mi][ni] = (floatx4){b, b, b, b};
    }

    for (int k0 = 0; k0 < 256; k0 += 32) {
        {   // A: 64 rows x 32 k
            int ga = row0 + tr; if (ga >= N) ga = N - 1;
            gload_lds16(concat + (size_t)ga * 256 + k0 + sk,
                        (char*)As + (size_t)tr * 64 + sk * 2);
        }
#pragma unroll
        for (int p = 0; p < 4; ++p) {   // B: 256 rows of W1T
            int rn = p * 64 + tr;
            gload_lds16(W1T + (size_t)rn * 256 + k0 + sk,
                        (char*)Bs + (size_t)rn * 64 + sk * 2);
        }
        __syncthreads();
        short8 af[4], bfr[4];
#pragma unroll
        for (int mi = 0; mi < 4; ++mi)
            af[mi] = *(const short8*)(As + (size_t)(mi * 16 + lm) * 32 + quad * 8);
#pragma unroll
        for (int ni = 0; ni < 4; ++ni)
            bfr[ni] = *(const short8*)(Bs + (size_t)(w * 64 + ni * 16 + lm) * 32 + quad * 8);
#pragma unroll
        for (int mi = 0; mi < 4; ++mi)
#pragma unroll
            for (int ni = 0; ni < 4; ++ni)
                acc[mi][ni] = __builtin_amdgcn_mfma_f32_16x16x32_bf16(af[mi], bfr[ni], acc[mi][ni], 0, 0, 0);
        __syncthreads();
    }

    // hidden -> Hs (relu, bf16)
#pragma unroll
    for (int mi = 0; mi < 4; ++mi)
#pragma unroll
        for (int ni = 0; ni < 4; ++ni)
#pragma unroll
            for (int q = 0; q < 4; ++q) {
                int row = mi * 16 + quad * 4 + q;
                int col = w * 64 + ni * 16 + lm;
                Hs[row * 264 + col] = f2bf(relu_nan(acc[mi][ni][q]));
            }

    // ---- stage 2: out = Hs @ W2 + b2, wave w owns cols w*32.. ----
    floatx4 acc2[4][2];
#pragma unroll
    for (int ni = 0; ni < 2; ++ni) {
        float b = b2[w * 32 + ni * 16 + lm];
#pragma unroll
        for (int mi = 0; mi < 4; ++mi) acc2[mi][ni] = (floatx4){b, b, b, b};
    }

    for (int k0 = 0; k0 < 256; k0 += 32) {
#pragma unroll
        for (int p = 0; p < 2; ++p) {   // B: 128 rows of W2T
            int rn = p * 64 + tr;
            gload_lds16(W2T + (size_t)rn * 256 + k0 + sk,
                        (char*)Bs + (size_t)rn * 64 + sk * 2);
        }
        __syncthreads();   // Bs2 staged AND (k0==0) Hs writes visible to all waves
        short8 af[4], bfr[2];
#pragma unroll
        for (int mi = 0; mi < 4; ++mi)
            af[mi] = *(const short8*)(Hs + (size_t)(mi * 16 + lm) * 264 + k0 + quad * 8);
#pragma unroll
        for (int ni = 0; ni < 2; ++ni)
            bfr[ni] = *(const short8*)(Bs + (size_t)(w * 32 + ni * 16 + lm) * 32 + quad * 8);
#pragma unroll
        for (int mi = 0; mi < 4; ++mi)
#pragma unroll
            for (int ni = 0; ni < 2; ++ni)
                acc2[mi][ni] = __builtin_amdgcn_mfma_f32_16x16x32_bf16(af[mi], bfr[ni], acc2[mi][ni], 0, 0, 0);
        __syncthreads();
    }

#pragma unroll
    for (int mi = 0; mi < 4; ++mi)
#pragma unroll
        for (int ni = 0; ni < 2; ++ni)
#pragma unroll
            for (int q = 0; q < 4; ++q) {
                int r = row0 + mi * 16 + quad * 4 + q;
                int c = w * 32 + ni * 16 + lm;
                if (r < N) outp[(size_t)r * 128 + c] = acc2[mi][ni][q];
            }
}

extern "C" void kernel_launch(void* const* d_in, const int* in_sizes, int n_in,
                              void* d_out, int out_size, void* d_ws, size_t ws_size,
                              hipStream_t stream) {
    const float* X    = (const float*)d_in[0];
    const int* src    = (const int*)d_in[1];
    const int* dst    = (const int*)d_in[2];
    const float* Wn   = (const float*)d_in[3];
    const float* Asrc = (const float*)d_in[4];
    const float* Adst = (const float*)d_in[5];
    const float* W1   = (const float*)d_in[6];
    const float* b1   = (const float*)d_in[7];
    const float* W2   = (const float*)d_in[8];
    const float* b2   = (const float*)d_in[9];
    float* out = (float*)d_out;

    const int N = in_sizes[0] / 128;   // 50000
    const int E = in_sizes[1];         // 800000
    const int NBS = (N + 255) / 256;   // scan blocks (must be <= 256)
    const int NR = (N + 127) / 128;    // gemm0 row tiles
    const int NM = (N + 63) / 64;      // k_mlp row tiles

    // ws layout (16B-aligned offsets), ~31 MB.
    size_t off = 0;
    char* w = (char*)d_ws;
    unsigned short* h_bf = (unsigned short*)(w + off); off += (size_t)N * 256 * 2;
    float* s_src = (float*)(w + off);                  off += (size_t)N * 4 * 4;
    float* s_dst = (float*)(w + off);                  off += (size_t)N * 4 * 4;
    int* cnt     = (int*)(w + off);                    off += (size_t)N * 4;
    int* rowptr  = (int*)(w + off);                    off += ((size_t)(N + 1) * 4 + 15) & ~15ull;
    int* wcnt    = (int*)(w + off);                    off += (size_t)N * 4;
    int* bsum    = (int*)(w + off);                    off += ((size_t)NBS * 4 + 15) & ~15ull;
    int* esrc    = (int*)(w + off);                    off += (size_t)E * 4;
    unsigned short* W1T = (unsigned short*)(w + off);  off += 256 * 256 * 2;
    unsigned short* W2T = (unsigned short*)(w + off);  off += 128 * 256 * 2;
    unsigned short* WnT = (unsigned short*)(w + off);  off += 256 * 128 * 2;
    const size_t required = off;

    if (ws_size < required) {
        k_fill<<<dim3((out_size + 255) / 256), dim3(256), 0, stream>>>(
            out, (float)(ws_size >> 20), out_size);
        return;
    }

    // d_out staging: concat (bf16 [N,256]) from k_agg -> consumed in-place by k_mlp,
    // which overwrites the same bytes with the final fp32 out.
    unsigned short* concat = (unsigned short*)d_out;

    hipMemsetAsync(cnt, 0, (size_t)N * sizeof(int), stream);
    k_prep<<<dim3(2048), dim3(256), 0, stream>>>(Wn, WnT, W1, W1T, W2, W2T, dst, cnt, E);
    // h = bf16(X) @ WnT (MFMA, A staged from fp32) + fused s_src/s_dst epilogue
    k_gemm0<<<dim3(NR, 2), dim3(256), 0, stream>>>(
        X, WnT, h_bf, N, Asrc, Adst, s_src, s_dst);
    k_scan1<<<dim3(NBS), dim3(256), 0, stream>>>(cnt, rowptr, bsum, N);
    k_scan23<<<dim3(NBS), dim3(256), 0, stream>>>(rowptr, bsum, wcnt, N, E);
    k_scatter<<<dim3((E + 255) / 256), dim3(256), 0, stream>>>(src, dst, wcnt, esrc, E);
    k_agg<<<dim3((N + 3) / 4), dim3(256), 0, stream>>>(s_src, s_dst, h_bf, rowptr, esrc,
                                                       concat, N);
    // fused MLP: out = relu(concat @ W1 + b1) @ W2 + b2   (in-place in d_out)
    k_mlp<<<dim3(NM), dim3(256), 0, stream>>>(concat, W1T, b1, W2T, b2, out, N);
}